// Round 2
// baseline (169.130 us; speedup 1.0000x reference)
//
#include <hip/hip_runtime.h>

// B=8, C=21, H=512, W=512 ; gt/pred int32 ; output = scalar f32
// mean over B of tp / max(tp+fp+fn, 1e-8)
//   valid = gt != 255 ; eq = gt==pred
//   gt_in = 1<=gt<21 ; pred_in = 1<=pred<21

#define N_CLASSES 21
#define IGNORE_LBL 255
#define BATCH 8
#define BLOCKS_PER_SAMPLE 256
#define THREADS 256
#define T_PER_SAMPLE (BLOCKS_PER_SAMPLE * THREADS)   // 65536
#define VEC_PER_SAMPLE 1376256                       // 21*512*512/4 = 21*65536
#define J_ITERS 21                                   // vectors per thread
#define TOTAL_BLOCKS (BLOCKS_PER_SAMPLE * BATCH)     // 2048

__device__ __forceinline__ void proc4(const int4& g, const int4& p,
                                      int& tp, int& fp, int& fn) {
    const int gv[4] = {g.x, g.y, g.z, g.w};
    const int pv[4] = {p.x, p.y, p.z, p.w};
#pragma unroll
    for (int k = 0; k < 4; ++k) {
        const int gk = gv[k], pk = pv[k];
        const int valid = (gk != IGNORE_LBL);
        const int eq = (gk == pk);
        const int gin = (gk >= 1) & (gk < N_CLASSES);
        const int pin = (pk >= 1) & (pk < N_CLASSES);
        tp += eq & gin & valid;
        fp += (eq ^ 1) & pin & valid;
        fn += (eq ^ 1) & gin & valid;
    }
}

// ws layout: u32 counts[BATCH*3] then u32 done_counter
__global__ __launch_bounds__(THREADS, 8) void iou_fused_kernel(
    const int* __restrict__ gt, const int* __restrict__ pred,
    unsigned int* __restrict__ ws, float* __restrict__ out) {
    const int b = blockIdx.y;
    const int tid = blockIdx.x * THREADS + threadIdx.x;  // 0..65535
    const int4* __restrict__ g4 =
        reinterpret_cast<const int4*>(gt) + (size_t)b * VEC_PER_SAMPLE + tid;
    const int4* __restrict__ p4 =
        reinterpret_cast<const int4*>(pred) + (size_t)b * VEC_PER_SAMPLE + tid;

    int tp = 0, fp = 0, fn = 0;

    // 5 batches of 4 int4-pairs (8 loads in flight), fully unrolled, + 1 tail
#pragma unroll
    for (int batch = 0; batch < 5; ++batch) {
        int4 gs[4], ps[4];
#pragma unroll
        for (int k = 0; k < 4; ++k) {
            gs[k] = g4[(size_t)(batch * 4 + k) * T_PER_SAMPLE];
            ps[k] = p4[(size_t)(batch * 4 + k) * T_PER_SAMPLE];
        }
#pragma unroll
        for (int k = 0; k < 4; ++k) proc4(gs[k], ps[k], tp, fp, fn);
    }
    {
        int4 g = g4[(size_t)20 * T_PER_SAMPLE];
        int4 p = p4[(size_t)20 * T_PER_SAMPLE];
        proc4(g, p, tp, fp, fn);
    }

    // wave (64-lane) reduce
#pragma unroll
    for (int off = 32; off > 0; off >>= 1) {
        tp += __shfl_down(tp, off);
        fp += __shfl_down(fp, off);
        fn += __shfl_down(fn, off);
    }

    __shared__ int s_tp[4], s_fp[4], s_fn[4];  // 256 threads = 4 waves
    const int wave = threadIdx.x >> 6;
    const int lane = threadIdx.x & 63;
    if (lane == 0) {
        s_tp[wave] = tp;
        s_fp[wave] = fp;
        s_fn[wave] = fn;
    }
    __syncthreads();

    if (threadIdx.x == 0) {
        int t = 0, f = 0, n = 0;
#pragma unroll
        for (int w = 0; w < 4; ++w) {
            t += s_tp[w];
            f += s_fp[w];
            n += s_fn[w];
        }
        atomicAdd(&ws[b * 3 + 0], (unsigned int)t);
        atomicAdd(&ws[b * 3 + 1], (unsigned int)f);
        atomicAdd(&ws[b * 3 + 2], (unsigned int)n);

        // last-block finalize (device-scope atomics; coherent across XCDs)
        __threadfence();
        const unsigned int prev = atomicAdd(&ws[BATCH * 3], 1u);
        if (prev == TOTAL_BLOCKS - 1) {
            __threadfence();
            float s = 0.0f;
#pragma unroll
            for (int bb = 0; bb < BATCH; ++bb) {
                const float tpf = (float)atomicAdd(&ws[bb * 3 + 0], 0u);
                const float fpf = (float)atomicAdd(&ws[bb * 3 + 1], 0u);
                const float fnf = (float)atomicAdd(&ws[bb * 3 + 2], 0u);
                s += tpf / fmaxf(tpf + fpf + fnf, 1e-8f);
            }
            out[0] = s / (float)BATCH;
        }
    }
}

extern "C" void kernel_launch(void* const* d_in, const int* in_sizes, int n_in,
                              void* d_out, int out_size, void* d_ws, size_t ws_size,
                              hipStream_t stream) {
    const int* gt = (const int*)d_in[0];
    const int* pred = (const int*)d_in[1];
    float* out = (float*)d_out;
    unsigned int* ws = (unsigned int*)d_ws;

    hipMemsetAsync(ws, 0, (BATCH * 3 + 1) * sizeof(unsigned int), stream);

    dim3 grid(BLOCKS_PER_SAMPLE, BATCH, 1);
    dim3 block(THREADS, 1, 1);
    iou_fused_kernel<<<grid, block, 0, stream>>>(gt, pred, ws, out);
}